// Round 8
// baseline (287.508 us; speedup 1.0000x reference)
//
#include <hip/hip_runtime.h>
#include <math.h>

#define BB  128
#define NN  1024
#define KNN 40
#define HH  64

// ---------------------------------------------------------------------------
// Kernel A: 40-NN selection + fused MLP max-pool + sigmoid weight.
// 4 waves/block, 16 rows/block (4 rows/wave), grid = 8192.
//
// REGISTER SHAPE IS LOAD-BEARING (R2/R4/R5): key[16] must stay in VGPRs;
// empirical law on this stack: VGPR budget ~= 256/launch_bounds_arg2.
// Only (256,4) (budget 64) fits this body. Do not tighten.
//
// Selection: count(pivot) = #{key < pivot} via v_cmp ballots + scalar
// popcounts. R8: THREE pivots per sweep (p2 = false-position estimate,
// p1/p3 = half-splits of the flanks; every subinterval <= width/2 ->
// guaranteed termination, typically ~4x shrink/iter). Exact exit when any
// count == 40; dup-inclusive thr=hi at width 1. Cuts the loop-carried
// {sweep -> scalar decide} chain from ~10-14 to ~4-6 iterations.
//
// Selected set carried as 16 wave-uniform u64 ballot masks (SGPR pairs).
// Pool(row r-1) is software-pipelined into the distance fill of row r and
// uses 4 independent accumulators (static t&3 rotation) so the fmax chain
// doesn't serialize the ~40 uniform broadcast ds_read_b128's (R7's main
// residual: one chain x ~120cy LDS latency each).
// ---------------------------------------------------------------------------
__global__ __launch_bounds__(256, 4) void knn_weight_kernel(
    const float* __restrict__ pts,  // [B,3,N]
    const float* __restrict__ W1,   // [3,H]
    const float* __restrict__ b1,   // [H]
    const float* __restrict__ W2,   // [H]
    const float* __restrict__ b2,   // [1]
    float* __restrict__ wout)       // [B,N]
{
    __shared__ float4 sp[NN];   // 16 KB: (x,y,z,0)

    const int b    = blockIdx.x >> 6;
    const int grp  = blockIdx.x & 63;
    const int tid  = threadIdx.x;
    const int w    = tid >> 6;
    const int lane = tid & 63;

    const float* px = pts + b * 3 * NN;
    for (int i = tid; i < NN; i += 256)
        sp[i] = make_float4(px[i], px[NN + i], px[2 * NN + i], 0.0f);
    __syncthreads();

    const float w1x = W1[lane];           // W1[0][lane]
    const float w1y = W1[HH + lane];      // W1[1][lane]
    const float w1z = W1[2 * HH + lane];  // W1[2][lane]
    const float b1v = b1[lane];
    const float w2v = W2[lane];
    const float b2v = b2[0];

    unsigned long long msk[16];           // wave-uniform ballots (SGPR pairs)
    #pragma unroll
    for (int t = 0; t < 16; ++t) msk[t] = 0ull;

    float pl0 = -__builtin_inff(), pl1 = -__builtin_inff();
    float pl2 = -__builtin_inff(), pl3 = -__builtin_inff();
    int   nP  = -1;                       // prev row id (-1 = none yet)

    for (int r = 0; r < 4; ++r) {
        const int n = grp * 16 + w * 4 + r;
        const float4 q = sp[n];

        // --- merged: pool(prev row, from masks) + distances(current row) ---
        unsigned key[16];
        unsigned lmin = 0xffffffffu;
        #pragma unroll
        for (int t = 0; t < 16; ++t) {
            // static accumulator rotation (t literal under full unroll)
            float& pa = ((t & 3) == 0) ? pl0 : ((t & 3) == 1) ? pl1
                       : ((t & 3) == 2) ? pl2 : pl3;
            float& pb = ((t & 3) == 0) ? pl1 : ((t & 3) == 1) ? pl2
                       : ((t & 3) == 2) ? pl3 : pl0;
            const float4 pc = sp[t * 64 + lane];    // per-lane vector load
            unsigned long long m = msk[t];          // uniform: pool prev row
            while (m) {
                const int i0 = (int)__ffsll(m) - 1; m &= m - 1;
                int i1 = -1;
                if (m) { i1 = (int)__ffsll(m) - 1; m &= m - 1; }
                const float4 c0 = sp[t * 64 + i0];  // uniform broadcast read
                pa = fmaxf(pa, fmaf(c0.x, w1x, fmaf(c0.y, w1y, c0.z * w1z)));
                if (i1 >= 0) {
                    const float4 c1 = sp[t * 64 + i1];
                    pb = fmaxf(pb, fmaf(c1.x, w1x, fmaf(c1.y, w1y, c1.z * w1z)));
                }
            }
            const float dx = pc.x - q.x, dy = pc.y - q.y, dz = pc.z - q.z;
            key[t] = __float_as_uint(fmaf(dx, dx, fmaf(dy, dy, dz * dz)));
            lmin = lmin < key[t] ? lmin : key[t];
        }

        // wave-max of per-lane minima -> upper bracket (cnt >= 64 >= 40)
        unsigned wmaxmin = lmin;
        #pragma unroll
        for (int s = 1; s < 64; s <<= 1) {
            const unsigned o = (unsigned)__shfl_xor((int)wmaxmin, s);
            wmaxmin = wmaxmin > o ? wmaxmin : o;
        }

        // --- 3-pivot false-position selection for the 40-NN threshold ---
        unsigned lo = 0u, hi = wmaxmin + 1u;
        float flo = 0.0f, fhi = __uint_as_float(hi);
        float clo = 0.0f, chi = 64.0f;    // chi: safe lower-bound estimate
        unsigned thr = 0u;
        int found = 0;
        while (hi - lo > 1u) {
            const float tt = (40.5f - clo) / (chi - clo);
            const float pf = flo + (fhi - flo) * tt;
            unsigned p2 = __float_as_uint(pf);
            if (p2 <= lo) p2 = lo + 1u;
            if (p2 >= hi) p2 = hi - 1u;
            const unsigned p1 = lo + ((p2 - lo) >> 1);
            const unsigned p3 = p2 + ((hi - p2) >> 1);
            int c1 = 0, c2 = 0, c3 = 0;
            #pragma unroll
            for (int t = 0; t < 16; ++t) {
                c1 += (int)__popcll(__ballot(key[t] < p1));
                c2 += (int)__popcll(__ballot(key[t] < p2));
                c3 += (int)__popcll(__ballot(key[t] < p3));
            }
            if (c1 == KNN) { thr = p1; found = 1; break; }
            if (c2 == KNN) { thr = p2; found = 1; break; }
            if (c3 == KNN) { thr = p3; found = 1; break; }
            if (c1 > KNN) {                       // 40th below p1
                hi = p1; fhi = __uint_as_float(p1); chi = (float)c1;
            } else if (c2 > KNN) {                // in [p1, p2)
                lo = p1; flo = __uint_as_float(p1); clo = (float)c1;
                hi = p2; fhi = __uint_as_float(p2); chi = (float)c2;
            } else if (c3 > KNN) {                // in [p2, p3)
                lo = p2; flo = __uint_as_float(p2); clo = (float)c2;
                hi = p3; fhi = __uint_as_float(p3); chi = (float)c3;
            } else {                              // in [p3, hi)
                lo = p3; flo = __uint_as_float(p3); clo = (float)c3;
            }
        }
        if (!found) thr = hi;   // boundary ties: dup-inclusive

        // --- selection masks for this row (consumed next iter / tail) ---
        #pragma unroll
        for (int t = 0; t < 16; ++t)
            msk[t] = __ballot(key[t] < thr);

        // --- finish prev row: sigmoid(relu(pool+b1)@W2 + b2) ---
        if (nP >= 0) {
            const float poolP = fmaxf(fmaxf(pl0, pl1), fmaxf(pl2, pl3));
            float acc = fmaxf(poolP + b1v, 0.0f) * w2v;
            #pragma unroll
            for (int s = 1; s < 64; s <<= 1) acc += __shfl_xor(acc, s);
            if (lane == 0)
                wout[b * NN + nP] = 1.0f / (1.0f + expf(-(acc + b2v)));
        }
        pl0 = pl1 = pl2 = pl3 = -__builtin_inff();
        nP = n;
    }

    // --- tail: pool + finish for the last row ---
    #pragma unroll
    for (int t = 0; t < 16; ++t) {
        float& pa = ((t & 3) == 0) ? pl0 : ((t & 3) == 1) ? pl1
                   : ((t & 3) == 2) ? pl2 : pl3;
        float& pb = ((t & 3) == 0) ? pl1 : ((t & 3) == 1) ? pl2
                   : ((t & 3) == 2) ? pl3 : pl0;
        unsigned long long m = msk[t];
        while (m) {
            const int i0 = (int)__ffsll(m) - 1; m &= m - 1;
            int i1 = -1;
            if (m) { i1 = (int)__ffsll(m) - 1; m &= m - 1; }
            const float4 c0 = sp[t * 64 + i0];
            pa = fmaxf(pa, fmaf(c0.x, w1x, fmaf(c0.y, w1y, c0.z * w1z)));
            if (i1 >= 0) {
                const float4 c1 = sp[t * 64 + i1];
                pb = fmaxf(pb, fmaf(c1.x, w1x, fmaf(c1.y, w1y, c1.z * w1z)));
            }
        }
    }
    {
        const float poolP = fmaxf(fmaxf(pl0, pl1), fmaxf(pl2, pl3));
        float acc = fmaxf(poolP + b1v, 0.0f) * w2v;
        #pragma unroll
        for (int s = 1; s < 64; s <<= 1) acc += __shfl_xor(acc, s);
        if (lane == 0)
            wout[b * NN + nP] = 1.0f / (1.0f + expf(-(acc + b2v)));
    }
}

// ---------------------------------------------------------------------------
// Kernel B: weighted order-2 jet fit per batch. One block (256 thr) per batch.
// ---------------------------------------------------------------------------
__global__ __launch_bounds__(256) void fit_kernel(
    const float* __restrict__ pts,   // [B,3,N]
    const float* __restrict__ wbuf,  // [B,N]
    float* __restrict__ out)         // [B,3]
{
    const int b    = blockIdx.x;
    const int tid  = threadIdx.x;
    const int lane = tid & 63;
    const int wv   = tid >> 6;
    const float* x    = pts + b * 3 * NN;
    const float* y    = x + NN;
    const float* z    = y + NN;
    const float* wrow = wbuf + b * NN;

    __shared__ float red[4][3];
    __shared__ float red27[4][27];
    __shared__ float sh_h;
    __shared__ int   sh_useW;

    // pass 1: mean|x|, mean|y|, valid_count
    float sax = 0.f, say = 0.f, cnt = 0.f;
    for (int i = tid; i < NN; i += 256) {
        sax += fabsf(x[i]);
        say += fabsf(y[i]);
        if (wrow[i] > 0.001f) cnt += 1.0f;
    }
    #pragma unroll
    for (int s = 1; s < 64; s <<= 1) {
        sax += __shfl_xor(sax, s);
        say += __shfl_xor(say, s);
        cnt += __shfl_xor(cnt, s);
    }
    if (lane == 0) { red[wv][0] = sax; red[wv][1] = say; red[wv][2] = cnt; }
    __syncthreads();
    if (tid == 0) {
        float SX = 0.f, SY = 0.f, C = 0.f;
        for (int q2 = 0; q2 < 4; ++q2) { SX += red[q2][0]; SY += red[q2][1]; C += red[q2][2]; }
        float h = (SX / (float)NN + SY / (float)NN) * 0.5f;
        if (fabsf(h) < 1e-4f) h = 0.1f;
        sh_h    = h;
        sh_useW = (C > 18.5f) ? 1 : 0;   // valid_count > 18
    }
    __syncthreads();
    const float h    = sh_h;
    const int   useW = sh_useW;
    const float ih   = 1.0f / h;

    // pass 2: XtX (21 unique) + XtY (6)
    float S[27];
    #pragma unroll
    for (int i = 0; i < 27; ++i) S[i] = 0.f;

    for (int i = tid; i < NN; i += 256) {
        const float wt = useW ? wrow[i] : 1.0f;
        const float xs = x[i] * ih;
        const float ys = y[i] * ih;
        const float zz = z[i];
        const float A[6] = { xs, ys, xs * xs, ys * ys, xs * ys, 1.0f };
        int c = 0;
        #pragma unroll
        for (int p = 0; p < 6; ++p) {
            const float wp = wt * A[p];
            #pragma unroll
            for (int q2 = p; q2 < 6; ++q2) {
                S[c] = fmaf(wp, A[q2], S[c]);
                ++c;
            }
            S[21 + p] = fmaf(wp, zz, S[21 + p]);
        }
    }
    #pragma unroll
    for (int i = 0; i < 27; ++i) {
        float v = S[i];
        #pragma unroll
        for (int s = 1; s < 64; s <<= 1) v += __shfl_xor(v, s);
        if (lane == 0) red27[wv][i] = v;
    }
    __syncthreads();

    if (tid == 0) {
        double T[27];
        for (int i = 0; i < 27; ++i)
            T[i] = (double)red27[0][i] + (double)red27[1][i]
                 + (double)red27[2][i] + (double)red27[3][i];

        double M[6][7];
        int c = 0;
        for (int p = 0; p < 6; ++p)
            for (int q2 = p; q2 < 6; ++q2) {
                M[p][q2] = T[c]; M[q2][p] = T[c]; ++c;
            }
        for (int p = 0; p < 6; ++p) M[p][6] = T[21 + p];

        // Gaussian elimination with partial pivoting (fp64, single thread)
        for (int col = 0; col < 6; ++col) {
            int piv = col; double best = fabs(M[col][col]);
            for (int rr = col + 1; rr < 6; ++rr) {
                const double a = fabs(M[rr][col]);
                if (a > best) { best = a; piv = rr; }
            }
            if (piv != col)
                for (int cc = col; cc < 7; ++cc) {
                    const double t = M[col][cc]; M[col][cc] = M[piv][cc]; M[piv][cc] = t;
                }
            const double f = 1.0 / M[col][col];
            for (int rr = col + 1; rr < 6; ++rr) {
                const double m = M[rr][col] * f;
                for (int cc = col; cc < 7; ++cc) M[rr][cc] -= m * M[col][cc];
            }
        }
        double beta[6];
        for (int rr = 5; rr >= 0; --rr) {
            double s = M[rr][6];
            for (int cc = rr + 1; cc < 6; ++cc) s -= M[rr][cc] * beta[cc];
            beta[rr] = s / M[rr][rr];
        }
        const double hd  = (double)h;
        const double nx  = -(beta[0] / hd);
        const double ny  = -(beta[1] / hd);
        const double nrm = sqrt(nx * nx + ny * ny + 1.0);
        out[b * 3 + 0] = (float)(nx / nrm);
        out[b * 3 + 1] = (float)(ny / nrm);
        out[b * 3 + 2] = (float)(1.0 / nrm);
    }
}

extern "C" void kernel_launch(void* const* d_in, const int* in_sizes, int n_in,
                              void* d_out, int out_size, void* d_ws, size_t ws_size,
                              hipStream_t stream) {
    const float* pts = (const float*)d_in[0];
    const float* W1  = (const float*)d_in[1];
    const float* b1  = (const float*)d_in[2];
    const float* W2  = (const float*)d_in[3];
    const float* b2  = (const float*)d_in[4];
    // d_in[5] = k (==40), compile-time constant here.
    float* wbuf = (float*)d_ws;   // [B*N] f32 = 512 KB scratch
    float* out  = (float*)d_out;  // [B,3] f32

    knn_weight_kernel<<<BB * (NN / 16), 256, 0, stream>>>(pts, W1, b1, W2, b2, wbuf);
    fit_kernel<<<BB, 256, 0, stream>>>(pts, wbuf, out);
}

// Round 10
// 210.510 us; speedup vs baseline: 1.3658x; 1.3658x over previous
//
#include <hip/hip_runtime.h>
#include <math.h>

#define BB  128
#define NN  1024
#define KNN 40
#define HH  64

// ---- DPP butterfly helpers: strides 1/2/4/8 in-VALU (~4cy) vs ds_swizzle (~25cy)
// NB: __builtin_amdgcn_update_dpp needs a CONSTANT ctrl -> template parameter.
template <int CTRL>
__device__ __forceinline__ unsigned dpp_bfly_u(unsigned v) {
    return (unsigned)__builtin_amdgcn_update_dpp(0, (int)v, CTRL, 0xf, 0xf, true);
}
template <int CTRL>
__device__ __forceinline__ float dpp_bfly_f(float v) {
    return __uint_as_float((unsigned)__builtin_amdgcn_update_dpp(
        0, (int)__float_as_uint(v), CTRL, 0xf, 0xf, true));
}
#define DPP_X1  0xB1   // quad_perm [1,0,3,2]  == xor 1
#define DPP_X2  0x4E   // quad_perm [2,3,0,1]  == xor 2
#define DPP_X4  0x141  // row_half_mirror      == xor 4
#define DPP_X8  0x140  // row_mirror           == xor 8

// ---------------------------------------------------------------------------
// Kernel A: 40-NN selection + fused MLP max-pool + sigmoid weight.
// 4 waves/block, 16 rows/block (4 rows/wave), grid = 8192.
//
// REGISTER SHAPE IS LOAD-BEARING (R2/R4/R5): key[16] must stay in VGPRs;
// empirical law on this stack: VGPR budget ~= 256/launch_bounds_arg2.
// Only (256,4) (budget 64) fits this body. Do not tighten.
//
// Selection (R7-proven): count(pivot) via 16 v_cmp ballots + scalar
// popcounts; bracket [0, wave_max(lane mins)+1]; false-position pivot with
// bisection safeguard every 3rd step; exact exit at cnt==40; dup-inclusive
// thr=hi at width 1. (R8's 3-pivot variant regressed: 3x v_cmp issue/iter,
// no proportional chain cut -- reverted.)
//
// Selected set carried as 16 wave-uniform u64 ballot masks (SGPR pairs).
// Pool(row r-1) software-pipelined into distance fill of row r, with FOUR
// independent accumulators (static t&3 rotation) to break the fmax chain
// threading the ~40 uniform broadcast ds_read_b128's.
//
// R9/R10: wmaxmin reduce via DPP butterfly (1/2/4/8) + shfl (16/32); per-row
// epilogues deferred -- pooled[r] kept in registers (literal-indexed under
// full unroll), ONE batched 4-wide butterfly + float4 store at the end.
// ---------------------------------------------------------------------------
__global__ __launch_bounds__(256, 4) void knn_weight_kernel(
    const float* __restrict__ pts,  // [B,3,N]
    const float* __restrict__ W1,   // [3,H]
    const float* __restrict__ b1,   // [H]
    const float* __restrict__ W2,   // [H]
    const float* __restrict__ b2,   // [1]
    float* __restrict__ wout)       // [B,N]
{
    __shared__ float4 sp[NN];   // 16 KB: (x,y,z,0)

    const int b    = blockIdx.x >> 6;
    const int grp  = blockIdx.x & 63;
    const int tid  = threadIdx.x;
    const int w    = tid >> 6;
    const int lane = tid & 63;

    const float* px = pts + b * 3 * NN;
    for (int i = tid; i < NN; i += 256)
        sp[i] = make_float4(px[i], px[NN + i], px[2 * NN + i], 0.0f);
    __syncthreads();

    const float w1x = W1[lane];           // W1[0][lane]
    const float w1y = W1[HH + lane];      // W1[1][lane]
    const float w1z = W1[2 * HH + lane];  // W1[2][lane]
    const float b1v = b1[lane];
    const float w2v = W2[lane];
    const float b2v = b2[0];

    unsigned long long msk[16];           // wave-uniform ballots (SGPR pairs)
    #pragma unroll
    for (int t = 0; t < 16; ++t) msk[t] = 0ull;

    float pl0 = -__builtin_inff(), pl1 = -__builtin_inff();
    float pl2 = -__builtin_inff(), pl3 = -__builtin_inff();
    float pooled[4];                      // literal-indexed (full unroll)

// mask-walk pool step for tile t_ into rotated accumulators pa_/pb_
#define POOL_T(t_, pa_, pb_) {                                              \
        unsigned long long m = msk[t_];                                     \
        while (m) {                                                         \
            const int i0 = (int)__ffsll(m) - 1; m &= m - 1;                 \
            const float4 c0 = sp[(t_) * 64 + i0];                           \
            pa_ = fmaxf(pa_, fmaf(c0.x, w1x, fmaf(c0.y, w1y, c0.z * w1z))); \
            if (m) {                                                        \
                const int i1 = (int)__ffsll(m) - 1; m &= m - 1;             \
                const float4 c1 = sp[(t_) * 64 + i1];                       \
                pb_ = fmaxf(pb_, fmaf(c1.x, w1x, fmaf(c1.y, w1y, c1.z * w1z))); \
            }                                                               \
        }                                                                   \
    }

    #pragma unroll
    for (int r = 0; r < 4; ++r) {
        const int n = grp * 16 + w * 4 + r;
        const float4 q = sp[n];

        // --- merged: pool(prev row, from masks) + distances(current row) ---
        unsigned key[16];
        unsigned lmin = 0xffffffffu;
        #pragma unroll
        for (int t = 0; t < 16; ++t) {
            const float4 pc = sp[t * 64 + lane];    // per-lane vector load
            if ((t & 3) == 0)      POOL_T(t, pl0, pl1)
            else if ((t & 3) == 1) POOL_T(t, pl1, pl2)
            else if ((t & 3) == 2) POOL_T(t, pl2, pl3)
            else                   POOL_T(t, pl3, pl0)
            const float dx = pc.x - q.x, dy = pc.y - q.y, dz = pc.z - q.z;
            key[t] = __float_as_uint(fmaf(dx, dx, fmaf(dy, dy, dz * dz)));
            lmin = lmin < key[t] ? lmin : key[t];
        }
        if (r > 0) {                              // collapse prev row's pool
            pooled[r - 1] = fmaxf(fmaxf(pl0, pl1), fmaxf(pl2, pl3));
            pl0 = pl1 = pl2 = pl3 = -__builtin_inff();
        }

        // wave-max of per-lane minima -> upper bracket (cnt >= 64 >= 40)
        unsigned wmaxmin = lmin;
        { unsigned o;
          o = dpp_bfly_u<DPP_X1>(wmaxmin); wmaxmin = wmaxmin > o ? wmaxmin : o;
          o = dpp_bfly_u<DPP_X2>(wmaxmin); wmaxmin = wmaxmin > o ? wmaxmin : o;
          o = dpp_bfly_u<DPP_X4>(wmaxmin); wmaxmin = wmaxmin > o ? wmaxmin : o;
          o = dpp_bfly_u<DPP_X8>(wmaxmin); wmaxmin = wmaxmin > o ? wmaxmin : o;
          o = (unsigned)__shfl_xor((int)wmaxmin, 16); wmaxmin = wmaxmin > o ? wmaxmin : o;
          o = (unsigned)__shfl_xor((int)wmaxmin, 32); wmaxmin = wmaxmin > o ? wmaxmin : o;
        }

        // --- false-position + periodic-bisection for the 40-NN threshold ---
        unsigned lo = 0u, hi = wmaxmin + 1u;
        float flo = 0.0f, fhi = __uint_as_float(hi);
        float clo = 0.0f, chi = 64.0f;    // chi: safe lower-bound estimate
        unsigned thr = 0u;
        int found = 0, ph = 0;
        while (hi - lo > 1u) {
            unsigned mid;
            if (ph == 2) {                          // every 3rd: safeguard
                mid = lo + ((hi - lo) >> 1);
                ph = 0;
            } else {
                const float tt = (40.5f - clo) / (chi - clo);
                const float pf = flo + (fhi - flo) * tt;
                mid = __float_as_uint(pf);
                if (mid <= lo) mid = lo + 1u;
                if (mid >= hi) mid = hi - 1u;
                ++ph;
            }
            int c = 0;
            #pragma unroll
            for (int t = 0; t < 16; ++t)
                c += (int)__popcll(__ballot(key[t] < mid));
            if (c == KNN) { thr = mid; found = 1; break; }
            if (c < KNN) { lo = mid; flo = __uint_as_float(mid); clo = (float)c; }
            else         { hi = mid; fhi = __uint_as_float(mid); chi = (float)c; }
        }
        if (!found) thr = hi;   // boundary ties: dup-inclusive

        // --- selection masks for this row (consumed next iter / tail) ---
        #pragma unroll
        for (int t = 0; t < 16; ++t)
            msk[t] = __ballot(key[t] < thr);
    }

    // --- tail: pool for the last row ---
    #pragma unroll
    for (int t = 0; t < 16; ++t) {
        if ((t & 3) == 0)      POOL_T(t, pl0, pl1)
        else if ((t & 3) == 1) POOL_T(t, pl1, pl2)
        else if ((t & 3) == 2) POOL_T(t, pl2, pl3)
        else                   POOL_T(t, pl3, pl0)
    }
    pooled[3] = fmaxf(fmaxf(pl0, pl1), fmaxf(pl2, pl3));

    // --- batched epilogue: 4 rows' sigmoid(relu(pool+b1)@W2 + b2) ---
    {
        float a0 = fmaxf(pooled[0] + b1v, 0.0f) * w2v;
        float a1 = fmaxf(pooled[1] + b1v, 0.0f) * w2v;
        float a2 = fmaxf(pooled[2] + b1v, 0.0f) * w2v;
        float a3 = fmaxf(pooled[3] + b1v, 0.0f) * w2v;
        a0 += dpp_bfly_f<DPP_X1>(a0); a1 += dpp_bfly_f<DPP_X1>(a1);
        a2 += dpp_bfly_f<DPP_X1>(a2); a3 += dpp_bfly_f<DPP_X1>(a3);
        a0 += dpp_bfly_f<DPP_X2>(a0); a1 += dpp_bfly_f<DPP_X2>(a1);
        a2 += dpp_bfly_f<DPP_X2>(a2); a3 += dpp_bfly_f<DPP_X2>(a3);
        a0 += dpp_bfly_f<DPP_X4>(a0); a1 += dpp_bfly_f<DPP_X4>(a1);
        a2 += dpp_bfly_f<DPP_X4>(a2); a3 += dpp_bfly_f<DPP_X4>(a3);
        a0 += dpp_bfly_f<DPP_X8>(a0); a1 += dpp_bfly_f<DPP_X8>(a1);
        a2 += dpp_bfly_f<DPP_X8>(a2); a3 += dpp_bfly_f<DPP_X8>(a3);
        a0 += __shfl_xor(a0, 16); a1 += __shfl_xor(a1, 16);
        a2 += __shfl_xor(a2, 16); a3 += __shfl_xor(a3, 16);
        a0 += __shfl_xor(a0, 32); a1 += __shfl_xor(a1, 32);
        a2 += __shfl_xor(a2, 32); a3 += __shfl_xor(a3, 32);
        if (lane == 0) {
            const int n0 = grp * 16 + w * 4;
            float4 o;
            o.x = 1.0f / (1.0f + expf(-(a0 + b2v)));
            o.y = 1.0f / (1.0f + expf(-(a1 + b2v)));
            o.z = 1.0f / (1.0f + expf(-(a2 + b2v)));
            o.w = 1.0f / (1.0f + expf(-(a3 + b2v)));
            *reinterpret_cast<float4*>(&wout[b * NN + n0]) = o;
        }
    }
#undef POOL_T
}

// ---------------------------------------------------------------------------
// Kernel B: weighted order-2 jet fit per batch. One block (256 thr) per batch.
// ---------------------------------------------------------------------------
__global__ __launch_bounds__(256) void fit_kernel(
    const float* __restrict__ pts,   // [B,3,N]
    const float* __restrict__ wbuf,  // [B,N]
    float* __restrict__ out)         // [B,3]
{
    const int b    = blockIdx.x;
    const int tid  = threadIdx.x;
    const int lane = tid & 63;
    const int wv   = tid >> 6;
    const float* x    = pts + b * 3 * NN;
    const float* y    = x + NN;
    const float* z    = y + NN;
    const float* wrow = wbuf + b * NN;

    __shared__ float red[4][3];
    __shared__ float red27[4][27];
    __shared__ float sh_h;
    __shared__ int   sh_useW;

    // pass 1: mean|x|, mean|y|, valid_count
    float sax = 0.f, say = 0.f, cnt = 0.f;
    for (int i = tid; i < NN; i += 256) {
        sax += fabsf(x[i]);
        say += fabsf(y[i]);
        if (wrow[i] > 0.001f) cnt += 1.0f;
    }
    #pragma unroll
    for (int s = 1; s < 64; s <<= 1) {
        sax += __shfl_xor(sax, s);
        say += __shfl_xor(say, s);
        cnt += __shfl_xor(cnt, s);
    }
    if (lane == 0) { red[wv][0] = sax; red[wv][1] = say; red[wv][2] = cnt; }
    __syncthreads();
    if (tid == 0) {
        float SX = 0.f, SY = 0.f, C = 0.f;
        for (int q2 = 0; q2 < 4; ++q2) { SX += red[q2][0]; SY += red[q2][1]; C += red[q2][2]; }
        float h = (SX / (float)NN + SY / (float)NN) * 0.5f;
        if (fabsf(h) < 1e-4f) h = 0.1f;
        sh_h    = h;
        sh_useW = (C > 18.5f) ? 1 : 0;   // valid_count > 18
    }
    __syncthreads();
    const float h    = sh_h;
    const int   useW = sh_useW;
    const float ih   = 1.0f / h;

    // pass 2: XtX (21 unique) + XtY (6)
    float S[27];
    #pragma unroll
    for (int i = 0; i < 27; ++i) S[i] = 0.f;

    for (int i = tid; i < NN; i += 256) {
        const float wt = useW ? wrow[i] : 1.0f;
        const float xs = x[i] * ih;
        const float ys = y[i] * ih;
        const float zz = z[i];
        const float A[6] = { xs, ys, xs * xs, ys * ys, xs * ys, 1.0f };
        int c = 0;
        #pragma unroll
        for (int p = 0; p < 6; ++p) {
            const float wp = wt * A[p];
            #pragma unroll
            for (int q2 = p; q2 < 6; ++q2) {
                S[c] = fmaf(wp, A[q2], S[c]);
                ++c;
            }
            S[21 + p] = fmaf(wp, zz, S[21 + p]);
        }
    }
    #pragma unroll
    for (int i = 0; i < 27; ++i) {
        float v = S[i];
        #pragma unroll
        for (int s = 1; s < 64; s <<= 1) v += __shfl_xor(v, s);
        if (lane == 0) red27[wv][i] = v;
    }
    __syncthreads();

    if (tid == 0) {
        double T[27];
        for (int i = 0; i < 27; ++i)
            T[i] = (double)red27[0][i] + (double)red27[1][i]
                 + (double)red27[2][i] + (double)red27[3][i];

        double M[6][7];
        int c = 0;
        for (int p = 0; p < 6; ++p)
            for (int q2 = p; q2 < 6; ++q2) {
                M[p][q2] = T[c]; M[q2][p] = T[c]; ++c;
            }
        for (int p = 0; p < 6; ++p) M[p][6] = T[21 + p];

        // Gaussian elimination with partial pivoting (fp64, single thread)
        for (int col = 0; col < 6; ++col) {
            int piv = col; double best = fabs(M[col][col]);
            for (int rr = col + 1; rr < 6; ++rr) {
                const double a = fabs(M[rr][col]);
                if (a > best) { best = a; piv = rr; }
            }
            if (piv != col)
                for (int cc = col; cc < 7; ++cc) {
                    const double t = M[col][cc]; M[col][cc] = M[piv][cc]; M[piv][cc] = t;
                }
            const double f = 1.0 / M[col][col];
            for (int rr = col + 1; rr < 6; ++rr) {
                const double m = M[rr][col] * f;
                for (int cc = col; cc < 7; ++cc) M[rr][cc] -= m * M[col][cc];
            }
        }
        double beta[6];
        for (int rr = 5; rr >= 0; --rr) {
            double s = M[rr][6];
            for (int cc = rr + 1; cc < 6; ++cc) s -= M[rr][cc] * beta[cc];
            beta[rr] = s / M[rr][rr];
        }
        const double hd  = (double)h;
        const double nx  = -(beta[0] / hd);
        const double ny  = -(beta[1] / hd);
        const double nrm = sqrt(nx * nx + ny * ny + 1.0);
        out[b * 3 + 0] = (float)(nx / nrm);
        out[b * 3 + 1] = (float)(ny / nrm);
        out[b * 3 + 2] = (float)(1.0 / nrm);
    }
}

extern "C" void kernel_launch(void* const* d_in, const int* in_sizes, int n_in,
                              void* d_out, int out_size, void* d_ws, size_t ws_size,
                              hipStream_t stream) {
    const float* pts = (const float*)d_in[0];
    const float* W1  = (const float*)d_in[1];
    const float* b1  = (const float*)d_in[2];
    const float* W2  = (const float*)d_in[3];
    const float* b2  = (const float*)d_in[4];
    // d_in[5] = k (==40), compile-time constant here.
    float* wbuf = (float*)d_ws;   // [B*N] f32 = 512 KB scratch
    float* out  = (float*)d_out;  // [B,3] f32

    knn_weight_kernel<<<BB * (NN / 16), 256, 0, stream>>>(pts, W1, b1, W2, b2, wbuf);
    fit_kernel<<<BB, 256, 0, stream>>>(pts, wbuf, out);
}